// Round 6
// baseline (84.232 us; speedup 1.0000x reference)
//
#include <hip/hip_runtime.h>
#include <hip/hip_fp16.h>

#define B_SZ 4096
#define T_SZ 200
#define IN_SZ 34
#define TILES (B_SZ * T_SZ / 64)   // 12800 tiles of 64 rows
#define XG_BLOCKS 1024              // 128 thr = 2 waves each -> 2048 waves
#define WAVES_TOTAL (XG_BLOCKS * 2)
#define WT_FLOATS 560               // 34*16 transposed W + 16 bias
// HIDDEN = 4, 4*H = 16 gates, gate order i,f,g,o (rows of W_ih/W_hh)
// xg layout: [b][j][t][i,f,g,o] fp16  (lane-contiguous streams for the scan)

__device__ __forceinline__ float sigf(float x) {
    return 1.0f / (1.0f + __expf(-x));
}
__device__ __forceinline__ float tanh_f(float x) {
    return 2.0f / (1.0f + __expf(-2.0f * x)) - 1.0f;
}

// broadcast lane L (0..3) of each quad to all 4 lanes of the quad via DPP
__device__ __forceinline__ float quad_bcast0(float v) {
    int s = __float_as_int(v);
    return __int_as_float(__builtin_amdgcn_update_dpp(s, s, 0x00, 0xf, 0xf, true));
}
__device__ __forceinline__ float quad_bcast1(float v) {
    int s = __float_as_int(v);
    return __int_as_float(__builtin_amdgcn_update_dpp(s, s, 0x55, 0xf, 0xf, true));
}
__device__ __forceinline__ float quad_bcast2(float v) {
    int s = __float_as_int(v);
    return __int_as_float(__builtin_amdgcn_update_dpp(s, s, 0xAA, 0xf, 0xf, true));
}
__device__ __forceinline__ float quad_bcast3(float v) {
    int s = __float_as_int(v);
    return __int_as_float(__builtin_amdgcn_update_dpp(s, s, 0xFF, 0xf, 0xf, true));
}

typedef const __attribute__((address_space(1))) unsigned int* gas_t;
typedef __attribute__((address_space(3))) unsigned int* las_t;

// Prep: Wt[k*16+g] = W_ih[g*34+k] (64B-aligned 16-gate rows -> wide s_loads),
// Wt[544+g] = b_ih[g]+b_hh[g]. Tiny, runs once per call.
__global__ __launch_bounds__(64) void prep_kernel(
    const float* __restrict__ W_ih, const float* __restrict__ b_ih,
    const float* __restrict__ b_hh, float* __restrict__ wt) {
  for (int i = threadIdx.x; i < WT_FLOATS; i += 64) {
    if (i < 544) {
      int k = i >> 4, g = i & 15;
      wt[i] = W_ih[g * IN_SZ + k];
    } else {
      wt[i] = b_ih[i - 544] + b_hh[i - 544];
    }
  }
}

// Phase 1: gates (fp16) = x @ W^T + bias, written to [b][j][t][ifgo].
// 2 waves/block, private LDS ping-pong per wave (no barriers), counted
// vmcnt(9) prefetch, transposed-weight table for wide scalar loads.
__global__ __launch_bounds__(128) void xgates_kernel(
    const float* __restrict__ x, const float* __restrict__ wt,
    __half* __restrict__ xg) {
  __shared__ float xs[2 * 2 * 64 * IN_SZ];  // [wave][buf][64*34] = 34,816 B
  const int lane = threadIdx.x & 63;
  const int wv = threadIdx.x >> 6;
  float* buf0 = &xs[wv * 2 * 64 * IN_SZ];
  float* buf1 = buf0 + 64 * IN_SZ;
  const int gw = blockIdx.x * 2 + wv;

  float bias[16];
  #pragma unroll
  for (int g = 0; g < 16; ++g) bias[g] = wt[544 + g];

  auto issue = [&](int tile, float* buf) {
    const float4* src = reinterpret_cast<const float4*>(x + (size_t)tile * 64 * IN_SZ);
    char* l = reinterpret_cast<char*>(buf);
    #pragma unroll
    for (int i = 0; i < 8; ++i)
      __builtin_amdgcn_global_load_lds((gas_t)(src + i * 64 + lane),
                                       (las_t)(l + i * 1024), 16, 0, 0);
    if (lane < 32)
      __builtin_amdgcn_global_load_lds((gas_t)(src + 512 + lane),
                                       (las_t)(l + 8192), 16, 0, 0);
  };  // 9 vmcnt ops per tile

  int tile = gw;
  if (tile < TILES) issue(tile, buf0);
  int cur = 0;
  #pragma unroll 1
  for (; tile < TILES; tile += WAVES_TOTAL) {
    int nxt = tile + WAVES_TOTAL;
    if (nxt < TILES) {
      issue(nxt, cur ? buf0 : buf1);
      // 9 newest outstanding = prefetch; everything older (this tile's loads,
      // previous tile's 4 stores) is drained.
      asm volatile("s_waitcnt vmcnt(9)" ::: "memory");
    } else {
      asm volatile("s_waitcnt vmcnt(0)" ::: "memory");
    }
    __builtin_amdgcn_sched_barrier(0);

    const float* buf = cur ? buf1 : buf0;
    float xr[IN_SZ];
    const float2* rp = reinterpret_cast<const float2*>(buf + lane * IN_SZ);
    #pragma unroll
    for (int k = 0; k < IN_SZ / 2; ++k) {
      float2 v = rp[k];
      xr[2 * k] = v.x;
      xr[2 * k + 1] = v.y;
    }
    float acc[16];
    #pragma unroll
    for (int g = 0; g < 16; ++g) acc[g] = bias[g];
    #pragma unroll
    for (int k = 0; k < IN_SZ; ++k) {
      #pragma unroll
      for (int g = 0; g < 16; ++g)
        acc[g] = fmaf(xr[k], wt[k * 16 + g], acc[g]);  // contiguous -> dwordx8
    }
    // store per gate-column j: uint2 {h2(i,f), h2(g,o)} at [b][j][t]
    unsigned r = (unsigned)tile * 64u + (unsigned)lane;
    unsigned bb = r / 200u;           // magic-mul
    unsigned tt = r - bb * 200u;
    uint2* xg2 = reinterpret_cast<uint2*>(xg);
    size_t base = (size_t)bb * 800u + tt;   // + j*200
    #pragma unroll
    for (int j = 0; j < 4; ++j) {
      union { __half2 h[2]; uint2 v; } u;
      u.h[0] = __floats2half2_rn(acc[0 + j], acc[4 + j]);
      u.h[1] = __floats2half2_rn(acc[8 + j], acc[12 + j]);
      xg2[base + (size_t)j * 200u] = u.v;
    }
    cur ^= 1;
  }
}

// Phase 2: recurrent scan. 4 lanes per batch element, lane j owns h_j/c_j.
// Lane stream is contiguous (1600B). Inline-asm dwordx4 loads + counted
// vmcnt force a real ping-pong pipeline (compiler defeated it before).
#define LD 10   // dwordx4 loads per batch = 20 steps
#define ISSUE(p_, buf_)                                                        \
  do {                                                                         \
    _Pragma("unroll") for (int u_ = 0; u_ < LD; ++u_)                          \
        asm volatile("global_load_dwordx4 %0, %1, off"                         \
                     : "=v"(buf_[u_])                                          \
                     : "v"((p_) + u_ * 16));                                   \
  } while (0)
#define WAITV(n_)                                                              \
  do {                                                                         \
    asm volatile("s_waitcnt vmcnt(" #n_ ")" ::: "memory");                     \
    __builtin_amdgcn_sched_barrier(0);                                         \
  } while (0)

__global__ __launch_bounds__(64) void lstm_scan(
    const __half* __restrict__ xg, const float* __restrict__ W_hh,
    const float* __restrict__ W_fc, const float* __restrict__ b_fc,
    float* __restrict__ out) {
  int tid = blockIdx.x * 64 + threadIdx.x;
  int b = tid >> 2;
  int j = tid & 3;
  float Wi[4], Wf[4], Wg[4], Wo[4];
  #pragma unroll
  for (int k = 0; k < 4; ++k) {
    Wi[k] = W_hh[(0 + j) * 4 + k];
    Wf[k] = W_hh[(4 + j) * 4 + k];
    Wg[k] = W_hh[(8 + j) * 4 + k];
    Wo[k] = W_hh[(12 + j) * 4 + k];
  }
  float h[4] = {0.f, 0.f, 0.f, 0.f};
  float c = 0.f;

  auto step = [&](unsigned lo, unsigned hi) {
    union { unsigned u; __half2 h2; } a, bb;
    a.u = lo;
    bb.u = hi;
    float2 p01 = __half22float2(a.h2);   // (i, f)
    float2 p23 = __half22float2(bb.h2);  // (g, o)
    float pi = p01.x, pf = p01.y, pg = p23.x, po = p23.y;
    #pragma unroll
    for (int k = 0; k < 4; ++k) {
      pi = fmaf(Wi[k], h[k], pi);
      pf = fmaf(Wf[k], h[k], pf);
      pg = fmaf(Wg[k], h[k], pg);
      po = fmaf(Wo[k], h[k], po);
    }
    float iv = sigf(pi);
    float fv = sigf(pf);
    float gv = tanh_f(pg);
    float ov = sigf(po);
    c = fmaf(fv, c, iv * gv);
    float hj = ov * tanh_f(c);
    h[0] = quad_bcast0(hj);
    h[1] = quad_bcast1(hj);
    h[2] = quad_bcast2(hj);
    h[3] = quad_bcast3(hj);
  };

  // lane stream base: b*6400 + j*1600 bytes; batch stride 160B (20 steps)
  const char* base = reinterpret_cast<const char*>(xg) +
                     (size_t)b * 6400 + (size_t)j * 1600;
  uint4 A[LD], Bb[LD];

  ISSUE(base, A);          // batch 0
  ISSUE(base + 160, Bb);   // batch 1

  #pragma unroll 1
  for (int p = 0; p < 4; ++p) {
    WAITV(10);             // drain A(2p), keep B(2p+1) in flight
    #pragma unroll
    for (int u = 0; u < LD; ++u) {
      step(A[u].x, A[u].y);
      step(A[u].z, A[u].w);
    }
    ISSUE(base + (size_t)(2 * p + 2) * 160, A);
    WAITV(10);             // drain B(2p+1), keep A(2p+2)
    #pragma unroll
    for (int u = 0; u < LD; ++u) {
      step(Bb[u].x, Bb[u].y);
      step(Bb[u].z, Bb[u].w);
    }
    ISSUE(base + (size_t)(2 * p + 3) * 160, Bb);
  }
  WAITV(10);               // drain A(8), keep B(9)
  #pragma unroll
  for (int u = 0; u < LD; ++u) {
    step(A[u].x, A[u].y);
    step(A[u].z, A[u].w);
  }
  WAITV(0);                // drain B(9)
  #pragma unroll
  for (int u = 0; u < LD; ++u) {
    step(Bb[u].x, Bb[u].y);
    step(Bb[u].z, Bb[u].w);
  }

  if (j < 3) {
    float acc = b_fc[j];
    #pragma unroll
    for (int k = 0; k < 4; ++k) acc = fmaf(W_fc[j * 4 + k], h[k], acc);
    out[b * 3 + j] = acc;
  }
}

// Fallback (only if workspace is too small): fused single kernel, W_ih in LDS.
__global__ __launch_bounds__(256) void lstm_fused(
    const float* __restrict__ x, const float* __restrict__ W_ih,
    const float* __restrict__ W_hh, const float* __restrict__ b_ih,
    const float* __restrict__ b_hh, const float* __restrict__ W_fc,
    const float* __restrict__ b_fc, float* __restrict__ out) {
  __shared__ float Ws[16 * IN_SZ];
  for (int i = threadIdx.x; i < 16 * IN_SZ; i += 256) Ws[i] = W_ih[i];
  __syncthreads();
  int tid = blockIdx.x * 256 + threadIdx.x;
  int b = tid >> 2;
  int j = tid & 3;
  float bi = b_ih[0 + j] + b_hh[0 + j];
  float bf = b_ih[4 + j] + b_hh[4 + j];
  float bg = b_ih[8 + j] + b_hh[8 + j];
  float bo = b_ih[12 + j] + b_hh[12 + j];
  float Wi[4], Wf[4], Wg[4], Wo[4];
  #pragma unroll
  for (int k = 0; k < 4; ++k) {
    Wi[k] = W_hh[(0 + j) * 4 + k];
    Wf[k] = W_hh[(4 + j) * 4 + k];
    Wg[k] = W_hh[(8 + j) * 4 + k];
    Wo[k] = W_hh[(12 + j) * 4 + k];
  }
  float h[4] = {0.f, 0.f, 0.f, 0.f};
  float c = 0.f;
  const float2* xp = reinterpret_cast<const float2*>(x + (size_t)b * T_SZ * IN_SZ);
  int lbase = (threadIdx.x & 63) & ~3;
  for (int t = 0; t < T_SZ; ++t) {
    float xr[IN_SZ];
    #pragma unroll
    for (int k = 0; k < IN_SZ / 2; ++k) {
      float2 v = xp[(size_t)t * (IN_SZ / 2) + k];
      xr[2 * k] = v.x;
      xr[2 * k + 1] = v.y;
    }
    float pi = bi, pf = bf, pg = bg, po = bo;
    #pragma unroll
    for (int k = 0; k < IN_SZ; ++k) {
      pi = fmaf(xr[k], Ws[(0 + j) * IN_SZ + k], pi);
      pf = fmaf(xr[k], Ws[(4 + j) * IN_SZ + k], pf);
      pg = fmaf(xr[k], Ws[(8 + j) * IN_SZ + k], pg);
      po = fmaf(xr[k], Ws[(12 + j) * IN_SZ + k], po);
    }
    #pragma unroll
    for (int k = 0; k < 4; ++k) {
      pi = fmaf(Wi[k], h[k], pi);
      pf = fmaf(Wf[k], h[k], pf);
      pg = fmaf(Wg[k], h[k], pg);
      po = fmaf(Wo[k], h[k], po);
    }
    float iv = sigf(pi);
    float fv = sigf(pf);
    float gv = tanh_f(pg);
    float ov = sigf(po);
    c = fmaf(fv, c, iv * gv);
    float hj = ov * tanh_f(c);
    h[0] = __shfl(hj, lbase + 0);
    h[1] = __shfl(hj, lbase + 1);
    h[2] = __shfl(hj, lbase + 2);
    h[3] = __shfl(hj, lbase + 3);
  }
  if (j < 3) {
    float acc = b_fc[j];
    #pragma unroll
    for (int k = 0; k < 4; ++k) acc = fmaf(W_fc[j * 4 + k], h[k], acc);
    out[b * 3 + j] = acc;
  }
}

extern "C" void kernel_launch(void* const* d_in, const int* in_sizes, int n_in,
                              void* d_out, int out_size, void* d_ws, size_t ws_size,
                              hipStream_t stream) {
  const float* x    = (const float*)d_in[0];
  const float* W_ih = (const float*)d_in[1];
  const float* W_hh = (const float*)d_in[2];
  const float* b_ih = (const float*)d_in[3];
  const float* b_hh = (const float*)d_in[4];
  const float* W_fc = (const float*)d_in[5];
  const float* b_fc = (const float*)d_in[6];
  float* out = (float*)d_out;

  const size_t xg_off = 4096;  // Wt table lives at ws[0..2240)
  const size_t need = xg_off + (size_t)B_SZ * T_SZ * 16 * sizeof(__half);
  if (ws_size >= need) {
    float* wt = (float*)d_ws;
    __half* xg = (__half*)((char*)d_ws + xg_off);
    hipLaunchKernelGGL(prep_kernel, dim3(1), dim3(64), 0, stream,
                       W_ih, b_ih, b_hh, wt);
    hipLaunchKernelGGL(xgates_kernel, dim3(XG_BLOCKS), dim3(128), 0, stream,
                       x, wt, xg);
    hipLaunchKernelGGL(lstm_scan, dim3(B_SZ * 4 / 64), dim3(64), 0, stream,
                       xg, W_hh, W_fc, b_fc, out);
  } else {
    hipLaunchKernelGGL(lstm_fused, dim3(B_SZ * 4 / 256), dim3(256), 0, stream,
                       x, W_ih, W_hh, b_ih, b_hh, W_fc, b_fc, out);
  }
}

// Round 8
// 82.291 us; speedup vs baseline: 1.0236x; 1.0236x over previous
//
#include <hip/hip_runtime.h>
#include <hip/hip_fp16.h>

#define B_SZ 4096
#define T_SZ 200
#define IN_SZ 34
#define TILES (B_SZ * T_SZ / 64)   // 12800 tiles of 64 rows
#define XG_BLOCKS 1024              // 128 thr = 2 waves each -> 2048 waves
#define WAVES_TOTAL (XG_BLOCKS * 2)
#define WT_FLOATS 560               // 34*16 transposed W + 16 bias
// HIDDEN = 4, 4*H = 16 gates, gate order i,f,g,o (rows of W_ih/W_hh)
// xg layout: [b][j][t][i,f,g,o] fp16  (lane-contiguous streams for the scan)

__device__ __forceinline__ float sigf(float x) {
    return 1.0f / (1.0f + __expf(-x));
}
__device__ __forceinline__ float tanh_f(float x) {
    return 2.0f / (1.0f + __expf(-2.0f * x)) - 1.0f;
}

// broadcast lane L (0..3) of each quad to all 4 lanes of the quad via DPP
__device__ __forceinline__ float quad_bcast0(float v) {
    int s = __float_as_int(v);
    return __int_as_float(__builtin_amdgcn_update_dpp(s, s, 0x00, 0xf, 0xf, true));
}
__device__ __forceinline__ float quad_bcast1(float v) {
    int s = __float_as_int(v);
    return __int_as_float(__builtin_amdgcn_update_dpp(s, s, 0x55, 0xf, 0xf, true));
}
__device__ __forceinline__ float quad_bcast2(float v) {
    int s = __float_as_int(v);
    return __int_as_float(__builtin_amdgcn_update_dpp(s, s, 0xAA, 0xf, 0xf, true));
}
__device__ __forceinline__ float quad_bcast3(float v) {
    int s = __float_as_int(v);
    return __int_as_float(__builtin_amdgcn_update_dpp(s, s, 0xFF, 0xf, 0xf, true));
}

typedef const __attribute__((address_space(1))) unsigned int* gas_t;
typedef __attribute__((address_space(3))) unsigned int* las_t;

// Prep: Wt[k*16+g] = W_ih[g*34+k] (64B-aligned 16-gate rows -> wide s_loads),
// Wt[544+g] = b_ih[g]+b_hh[g]. Tiny, runs once per call.
__global__ __launch_bounds__(64) void prep_kernel(
    const float* __restrict__ W_ih, const float* __restrict__ b_ih,
    const float* __restrict__ b_hh, float* __restrict__ wt) {
  for (int i = threadIdx.x; i < WT_FLOATS; i += 64) {
    if (i < 544) {
      int k = i >> 4, g = i & 15;
      wt[i] = W_ih[g * IN_SZ + k];
    } else {
      wt[i] = b_ih[i - 544] + b_hh[i - 544];
    }
  }
}

// Phase 1: gates (fp16) = x @ W^T + bias, written to [b][j][t][ifgo].
// 2 waves/block, private LDS ping-pong per wave (no barriers), counted
// vmcnt(9) prefetch, transposed-weight table for wide scalar loads.
__global__ __launch_bounds__(128) void xgates_kernel(
    const float* __restrict__ x, const float* __restrict__ wt,
    __half* __restrict__ xg) {
  __shared__ float xs[2 * 2 * 64 * IN_SZ];  // [wave][buf][64*34] = 34,816 B
  const int lane = threadIdx.x & 63;
  const int wv = threadIdx.x >> 6;
  float* buf0 = &xs[wv * 2 * 64 * IN_SZ];
  float* buf1 = buf0 + 64 * IN_SZ;
  const int gw = blockIdx.x * 2 + wv;

  float bias[16];
  #pragma unroll
  for (int g = 0; g < 16; ++g) bias[g] = wt[544 + g];

  auto issue = [&](int tile, float* buf) {
    const float4* src = reinterpret_cast<const float4*>(x + (size_t)tile * 64 * IN_SZ);
    char* l = reinterpret_cast<char*>(buf);
    #pragma unroll
    for (int i = 0; i < 8; ++i)
      __builtin_amdgcn_global_load_lds((gas_t)(src + i * 64 + lane),
                                       (las_t)(l + i * 1024), 16, 0, 0);
    if (lane < 32)
      __builtin_amdgcn_global_load_lds((gas_t)(src + 512 + lane),
                                       (las_t)(l + 8192), 16, 0, 0);
  };  // 9 vmcnt ops per tile

  int tile = gw;
  if (tile < TILES) issue(tile, buf0);
  int cur = 0;
  #pragma unroll 1
  for (; tile < TILES; tile += WAVES_TOTAL) {
    int nxt = tile + WAVES_TOTAL;
    if (nxt < TILES) {
      issue(nxt, cur ? buf0 : buf1);
      // 9 newest outstanding = prefetch; everything older (this tile's loads,
      // previous tile's 4 stores) is drained.
      asm volatile("s_waitcnt vmcnt(9)" ::: "memory");
    } else {
      asm volatile("s_waitcnt vmcnt(0)" ::: "memory");
    }
    __builtin_amdgcn_sched_barrier(0);

    const float* buf = cur ? buf1 : buf0;
    float xr[IN_SZ];
    const float2* rp = reinterpret_cast<const float2*>(buf + lane * IN_SZ);
    #pragma unroll
    for (int k = 0; k < IN_SZ / 2; ++k) {
      float2 v = rp[k];
      xr[2 * k] = v.x;
      xr[2 * k + 1] = v.y;
    }
    float acc[16];
    #pragma unroll
    for (int g = 0; g < 16; ++g) acc[g] = bias[g];
    #pragma unroll
    for (int k = 0; k < IN_SZ; ++k) {
      #pragma unroll
      for (int g = 0; g < 16; ++g)
        acc[g] = fmaf(xr[k], wt[k * 16 + g], acc[g]);  // contiguous -> dwordx8
    }
    // store per gate-column j: uint2 {h2(i,f), h2(g,o)} at [b][j][t]
    unsigned r = (unsigned)tile * 64u + (unsigned)lane;
    unsigned bb = r / 200u;           // magic-mul
    unsigned tt = r - bb * 200u;
    uint2* xg2 = reinterpret_cast<uint2*>(xg);
    size_t base = (size_t)bb * 800u + tt;   // + j*200
    #pragma unroll
    for (int j = 0; j < 4; ++j) {
      union { __half2 h[2]; uint2 v; } u;
      u.h[0] = __floats2half2_rn(acc[0 + j], acc[4 + j]);
      u.h[1] = __floats2half2_rn(acc[8 + j], acc[12 + j]);
      xg2[base + (size_t)j * 200u] = u.v;
    }
    cur ^= 1;
  }
}

// Phase 2: recurrent scan. 4 lanes per batch element, lane j owns h_j/c_j.
// Lane stream is contiguous (1600B). One asm block per batch issues 10
// dwordx4 loads into NAMED uint4 values (no arrays -> no scratch), shared
// base address + offset:N immediates. Counted vmcnt ping-pong.
#define ISSUE10(P, r)                                                          \
  asm volatile("global_load_dwordx4 %0, %[p], off\n\t"                         \
               "global_load_dwordx4 %1, %[p], off offset:16\n\t"               \
               "global_load_dwordx4 %2, %[p], off offset:32\n\t"               \
               "global_load_dwordx4 %3, %[p], off offset:48\n\t"               \
               "global_load_dwordx4 %4, %[p], off offset:64\n\t"               \
               "global_load_dwordx4 %5, %[p], off offset:80\n\t"               \
               "global_load_dwordx4 %6, %[p], off offset:96\n\t"               \
               "global_load_dwordx4 %7, %[p], off offset:112\n\t"              \
               "global_load_dwordx4 %8, %[p], off offset:128\n\t"              \
               "global_load_dwordx4 %9, %[p], off offset:144"                  \
               : "=&v"(r##0), "=&v"(r##1), "=&v"(r##2), "=&v"(r##3),           \
                 "=&v"(r##4), "=&v"(r##5), "=&v"(r##6), "=&v"(r##7),           \
                 "=&v"(r##8), "=&v"(r##9)                                      \
               : [p] "v"(P))

#define WAITV(n_)                                                              \
  do {                                                                         \
    asm volatile("s_waitcnt vmcnt(" #n_ ")" ::: "memory");                     \
    __builtin_amdgcn_sched_barrier(0);                                         \
  } while (0)

// NOTE: paste only r##N (valid identifier); member access in this layer.
#define STEP4(v)                                                               \
  step((v).x, (v).y);                                                          \
  step((v).z, (v).w)
#define STEPS(r)                                                               \
  STEP4(r##0); STEP4(r##1); STEP4(r##2); STEP4(r##3); STEP4(r##4);             \
  STEP4(r##5); STEP4(r##6); STEP4(r##7); STEP4(r##8); STEP4(r##9)

__global__ __launch_bounds__(64) void lstm_scan(
    const __half* __restrict__ xg, const float* __restrict__ W_hh,
    const float* __restrict__ W_fc, const float* __restrict__ b_fc,
    float* __restrict__ out) {
  int tid = blockIdx.x * 64 + threadIdx.x;
  int b = tid >> 2;
  int j = tid & 3;
  float Wi[4], Wf[4], Wg[4], Wo[4];
  #pragma unroll
  for (int k = 0; k < 4; ++k) {
    Wi[k] = W_hh[(0 + j) * 4 + k];
    Wf[k] = W_hh[(4 + j) * 4 + k];
    Wg[k] = W_hh[(8 + j) * 4 + k];
    Wo[k] = W_hh[(12 + j) * 4 + k];
  }
  float h[4] = {0.f, 0.f, 0.f, 0.f};
  float c = 0.f;

  auto step = [&](unsigned lo, unsigned hi) {
    union { unsigned u; __half2 h2; } a_, b_;
    a_.u = lo;
    b_.u = hi;
    float2 p01 = __half22float2(a_.h2);  // (i, f)
    float2 p23 = __half22float2(b_.h2);  // (g, o)
    float pi = p01.x, pf = p01.y, pg = p23.x, po = p23.y;
    #pragma unroll
    for (int k = 0; k < 4; ++k) {
      pi = fmaf(Wi[k], h[k], pi);
      pf = fmaf(Wf[k], h[k], pf);
      pg = fmaf(Wg[k], h[k], pg);
      po = fmaf(Wo[k], h[k], po);
    }
    float iv = sigf(pi);
    float fv = sigf(pf);
    float gv = tanh_f(pg);
    float ov = sigf(po);
    c = fmaf(fv, c, iv * gv);
    float hj = ov * tanh_f(c);
    h[0] = quad_bcast0(hj);
    h[1] = quad_bcast1(hj);
    h[2] = quad_bcast2(hj);
    h[3] = quad_bcast3(hj);
  };

  // lane stream base: b*6400 + j*1600 bytes; batch = 10 dwordx4 = 20 steps
  const char* base = reinterpret_cast<const char*>(xg) +
                     (size_t)b * 6400 + (size_t)j * 1600;
  uint4 a0, a1, a2, a3, a4, a5, a6, a7, a8, a9;
  uint4 b0, b1, b2, b3, b4, b5, b6, b7, b8, b9;

  ISSUE10(base, a);         // batch 0
  ISSUE10(base + 160, b);   // batch 1
  const char* pa = base + 320;
  const char* pb = base + 480;

  #pragma unroll 1
  for (int it = 0; it < 4; ++it) {
    WAITV(10);              // FIFO: drains current a batch, keeps b's 10
    STEPS(a);
    ISSUE10(pa, a);
    pa += 320;
    WAITV(10);              // drains b batch, keeps new a's 10
    STEPS(b);
    ISSUE10(pb, b);
    pb += 320;
  }
  WAITV(10);                // drain batch 8
  STEPS(a);
  WAITV(0);                 // drain batch 9
  STEPS(b);

  if (j < 3) {
    float acc = b_fc[j];
    #pragma unroll
    for (int k = 0; k < 4; ++k) acc = fmaf(W_fc[j * 4 + k], h[k], acc);
    out[b * 3 + j] = acc;
  }
}

// Fallback (only if workspace is too small): fused single kernel, W_ih in LDS.
__global__ __launch_bounds__(256) void lstm_fused(
    const float* __restrict__ x, const float* __restrict__ W_ih,
    const float* __restrict__ W_hh, const float* __restrict__ b_ih,
    const float* __restrict__ b_hh, const float* __restrict__ W_fc,
    const float* __restrict__ b_fc, float* __restrict__ out) {
  __shared__ float Ws[16 * IN_SZ];
  for (int i = threadIdx.x; i < 16 * IN_SZ; i += 256) Ws[i] = W_ih[i];
  __syncthreads();
  int tid = blockIdx.x * 256 + threadIdx.x;
  int b = tid >> 2;
  int j = tid & 3;
  float bi = b_ih[0 + j] + b_hh[0 + j];
  float bf = b_ih[4 + j] + b_hh[4 + j];
  float bg = b_ih[8 + j] + b_hh[8 + j];
  float bo = b_ih[12 + j] + b_hh[12 + j];
  float Wi[4], Wf[4], Wg[4], Wo[4];
  #pragma unroll
  for (int k = 0; k < 4; ++k) {
    Wi[k] = W_hh[(0 + j) * 4 + k];
    Wf[k] = W_hh[(4 + j) * 4 + k];
    Wg[k] = W_hh[(8 + j) * 4 + k];
    Wo[k] = W_hh[(12 + j) * 4 + k];
  }
  float h[4] = {0.f, 0.f, 0.f, 0.f};
  float c = 0.f;
  const float2* xp = reinterpret_cast<const float2*>(x + (size_t)b * T_SZ * IN_SZ);
  int lbase = (threadIdx.x & 63) & ~3;
  for (int t = 0; t < T_SZ; ++t) {
    float xr[IN_SZ];
    #pragma unroll
    for (int k = 0; k < IN_SZ / 2; ++k) {
      float2 v = xp[(size_t)t * (IN_SZ / 2) + k];
      xr[2 * k] = v.x;
      xr[2 * k + 1] = v.y;
    }
    float pi = bi, pf = bf, pg = bg, po = bo;
    #pragma unroll
    for (int k = 0; k < IN_SZ; ++k) {
      pi = fmaf(xr[k], Ws[(0 + j) * IN_SZ + k], pi);
      pf = fmaf(xr[k], Ws[(4 + j) * IN_SZ + k], pf);
      pg = fmaf(xr[k], Ws[(8 + j) * IN_SZ + k], pg);
      po = fmaf(xr[k], Ws[(12 + j) * IN_SZ + k], po);
    }
    #pragma unroll
    for (int k = 0; k < 4; ++k) {
      pi = fmaf(Wi[k], h[k], pi);
      pf = fmaf(Wf[k], h[k], pf);
      pg = fmaf(Wg[k], h[k], pg);
      po = fmaf(Wo[k], h[k], po);
    }
    float iv = sigf(pi);
    float fv = sigf(pf);
    float gv = tanh_f(pg);
    float ov = sigf(po);
    c = fmaf(fv, c, iv * gv);
    float hj = ov * tanh_f(c);
    h[0] = __shfl(hj, lbase + 0);
    h[1] = __shfl(hj, lbase + 1);
    h[2] = __shfl(hj, lbase + 2);
    h[3] = __shfl(hj, lbase + 3);
  }
  if (j < 3) {
    float acc = b_fc[j];
    #pragma unroll
    for (int k = 0; k < 4; ++k) acc = fmaf(W_fc[j * 4 + k], h[k], acc);
    out[b * 3 + j] = acc;
  }
}

extern "C" void kernel_launch(void* const* d_in, const int* in_sizes, int n_in,
                              void* d_out, int out_size, void* d_ws, size_t ws_size,
                              hipStream_t stream) {
  const float* x    = (const float*)d_in[0];
  const float* W_ih = (const float*)d_in[1];
  const float* W_hh = (const float*)d_in[2];
  const float* b_ih = (const float*)d_in[3];
  const float* b_hh = (const float*)d_in[4];
  const float* W_fc = (const float*)d_in[5];
  const float* b_fc = (const float*)d_in[6];
  float* out = (float*)d_out;

  const size_t xg_off = 4096;  // Wt table lives at ws[0..2240)
  const size_t need = xg_off + (size_t)B_SZ * T_SZ * 16 * sizeof(__half);
  if (ws_size >= need) {
    float* wt = (float*)d_ws;
    __half* xg = (__half*)((char*)d_ws + xg_off);
    hipLaunchKernelGGL(prep_kernel, dim3(1), dim3(64), 0, stream,
                       W_ih, b_ih, b_hh, wt);
    hipLaunchKernelGGL(xgates_kernel, dim3(XG_BLOCKS), dim3(128), 0, stream,
                       x, wt, xg);
    hipLaunchKernelGGL(lstm_scan, dim3(B_SZ * 4 / 64), dim3(64), 0, stream,
                       xg, W_hh, W_fc, b_fc, out);
  } else {
    hipLaunchKernelGGL(lstm_fused, dim3(B_SZ * 4 / 256), dim3(256), 0, stream,
                       x, W_ih, W_hh, b_ih, b_hh, W_fc, b_fc, out);
  }
}